// Round 1
// baseline (419.936 us; speedup 1.0000x reference)
//
#include <hip/hip_runtime.h>
#include <hip/hip_bf16.h>
#include <stdint.h>

typedef __attribute__((ext_vector_type(8))) short bf16x8;
typedef __attribute__((ext_vector_type(4))) float f32x4;

__device__ __forceinline__ unsigned f2bf(float f){
  unsigned u = __builtin_bit_cast(unsigned, f);
  return (u + 0x7FFFu + ((u >> 16) & 1u)) >> 16;   // RNE truncate to bf16
}
__device__ __forceinline__ float bf2f(unsigned s){
  unsigned u = s << 16; return __builtin_bit_cast(float, u);
}

// ---------- convert x (fp32) -> bf16, 4 elems/thread ----------
__global__ void k_cvt_x(const float* __restrict__ x, uint2* __restrict__ xb, int n4){
  int t = blockIdx.x * 256 + threadIdx.x;
  if (t >= n4) return;
  float4 v = reinterpret_cast<const float4*>(x)[t];
  uint2 o;
  o.x = f2bf(v.x) | (f2bf(v.y) << 16);
  o.y = f2bf(v.z) | (f2bf(v.w) << 16);
  xb[t] = o;
}

// ---------- build stacked transposed bf16 weights ----------
// Wt1[o][r*128+k] = W1[r][k][o] (r<8) ; Wt1[o][1024+k] = root1[k][o]   (o<128)
// Wt2[o][r*128+k] = W2[r][k][o] (r<8) ; Wt2[o][1024+k] = root2[k][o]   (o<64)
__global__ void k_cvt_w(const float* __restrict__ W1, const float* __restrict__ r1,
                        const float* __restrict__ W2, const float* __restrict__ r2,
                        short* __restrict__ Wt1, short* __restrict__ Wt2){
  int t = blockIdx.x * 256 + threadIdx.x;
  if (t < 128 * 1152){
    int o = t / 1152, ka = t - o * 1152, r = ka >> 7, k = ka & 127;
    float v = (r < 8) ? W1[(r * 128 + k) * 128 + o] : r1[k * 128 + o];
    Wt1[t] = (short)f2bf(v);
  } else if (t < 128 * 1152 + 64 * 1152){
    int t2 = t - 128 * 1152;
    int o = t2 / 1152, ka = t2 - o * 1152, r = ka >> 7, k = ka & 127;
    float v = (r < 8) ? W2[(r * 128 + k) * 64 + o] : r2[k * 64 + o];
    Wt2[t2] = (short)f2bf(v);
  }
}

// ---------- per-(rel,dst) degree + per-dst edge count ----------
__global__ void k_count(const int* __restrict__ ei, const int* __restrict__ et,
                        int* __restrict__ cnt, int* __restrict__ degr, int E, int N){
  int e = blockIdx.x * 256 + threadIdx.x;
  if (e >= E) return;
  unsigned dst = (unsigned)ei[E + e];
  int rel = et[e] & 7;
  if (dst < (unsigned)N){
    atomicAdd(&cnt[dst], 1);
    atomicAdd(&degr[rel * N + dst], 1);
  }
}

// ---------- hierarchical exclusive scan of cnt -> offs ----------
__global__ void k_scan1(const int* __restrict__ cnt, int* __restrict__ incl,
                        int* __restrict__ bsum, int N){
  __shared__ int s[256];
  int i = blockIdx.x * 256 + threadIdx.x;
  int v = (i < N) ? cnt[i] : 0;
  s[threadIdx.x] = v; __syncthreads();
  for (int d = 1; d < 256; d <<= 1){
    int t = (threadIdx.x >= d) ? s[threadIdx.x - d] : 0;
    __syncthreads();
    s[threadIdx.x] += t;
    __syncthreads();
  }
  if (i < N) incl[i] = s[threadIdx.x];
  if (threadIdx.x == 255) bsum[blockIdx.x] = s[255];
}
__global__ void k_scan2(int* bsum, int NB){
  __shared__ int s[256];
  int t = threadIdx.x;
  int v = (t < NB) ? bsum[t] : 0;
  s[t] = v; __syncthreads();
  for (int d = 1; d < 256; d <<= 1){
    int u = (t >= d) ? s[t - d] : 0;
    __syncthreads();
    s[t] += u;
    __syncthreads();
  }
  if (t < NB) bsum[t] = s[t];
}
__global__ void k_fin(const int* __restrict__ cnt, const int* __restrict__ incl,
                      const int* __restrict__ bsum, int* __restrict__ offs, int N){
  int i = blockIdx.x * 256 + threadIdx.x;
  if (i >= N) return;
  int base = (blockIdx.x > 0) ? bsum[blockIdx.x - 1] : 0;
  offs[i] = base + incl[i] - cnt[i];
}

// ---------- scatter edges into CSR slots: payload = src | (rel<<16) ----------
__global__ void k_fill(const int* __restrict__ ei, const int* __restrict__ et,
                       const int* __restrict__ offs, int* __restrict__ fill,
                       unsigned* __restrict__ idx, int E, int N){
  int e = blockIdx.x * 256 + threadIdx.x;
  if (e >= E) return;
  unsigned src = (unsigned)ei[e];
  unsigned dst = (unsigned)ei[E + e];
  int rel = et[e] & 7;
  if (dst < (unsigned)N){
    int p = atomicAdd(&fill[dst], 1);
    idx[offs[dst] + p] = (src & 0xFFFFu) | ((unsigned)rel << 16);
  }
}

// ---------- wave-per-dst aggregation: A[dst] = [agg_r0..agg_r7 | feat[dst]] ----------
__global__ __launch_bounds__(256)
void k_agg(const short* __restrict__ feat, const int* __restrict__ cnt,
           const int* __restrict__ offs, const unsigned* __restrict__ idx,
           const int* __restrict__ degr, short* __restrict__ Aout, int N){
  int w = (blockIdx.x * 256 + threadIdx.x) >> 6;
  int lane = threadIdx.x & 63;
  if (w >= N) return;
  int dst = w;
  float a0[8], a1[8];
  #pragma unroll
  for (int r = 0; r < 8; r++){ a0[r] = 0.f; a1[r] = 0.f; }
  int n = cnt[dst], base = offs[dst];
  for (int j = 0; j < n; j++){
    unsigned p = idx[base + j];
    p = (unsigned)__builtin_amdgcn_readfirstlane((int)p);   // wave-uniform
    int rel = (int)(p >> 16);
    int src = (int)(p & 0xFFFFu);
    float coef = 1.0f / (float)degr[rel * N + dst];
    unsigned u = *reinterpret_cast<const unsigned*>(feat + src * 128 + lane * 2);
    float f0 = bf2f(u & 0xFFFFu), f1 = bf2f(u >> 16);
    #pragma unroll
    for (int r = 0; r < 8; r++){
      float cc = (rel == r) ? coef : 0.f;
      a0[r] = fmaf(cc, f0, a0[r]);
      a1[r] = fmaf(cc, f1, a1[r]);
    }
  }
  unsigned* orow = reinterpret_cast<unsigned*>(Aout + (size_t)dst * 1152);
  #pragma unroll
  for (int r = 0; r < 8; r++)
    orow[r * 64 + lane] = f2bf(a0[r]) | (f2bf(a1[r]) << 16);
  // copy the node's own features into the root slot (cols 1024..1151)
  orow[512 + lane] = *reinterpret_cast<const unsigned*>(feat + dst * 128 + lane * 2);
}

// ---------- GEMM: out[M][BN] = A[M][1152] x Wt^T + bias, fused epilogue ----------
// MODE 1: h = bf16(relu(v) * mask)   MODE 2: out fp32 = v
template<int NF, int MODE>
__global__ __launch_bounds__(256, 2)
void k_gemm(const short* __restrict__ A, const short* __restrict__ Wt,
            const float* __restrict__ bias, const float* __restrict__ mask,
            void* __restrict__ outp, int M){
  constexpr int BN = NF * 16;
  __shared__ uint4 sA[128 * 16];
  __shared__ uint4 sB[BN * 16];
  int tid = threadIdx.x, lane = tid & 63, wave = tid >> 6;
  int row0 = blockIdx.x * 128;
  f32x4 acc[2][NF];
  f32x4 z = {0.f, 0.f, 0.f, 0.f};
  #pragma unroll
  for (int m = 0; m < 2; m++)
    #pragma unroll
    for (int n = 0; n < NF; n++) acc[m][n] = z;

  for (int kc = 0; kc < 9; kc++){
    for (int it = tid; it < 128 * 16; it += 256){
      int r = it >> 4, c = it & 15;
      int grow = row0 + r;
      uint4 v = {0u, 0u, 0u, 0u};
      if (grow < M) v = *reinterpret_cast<const uint4*>(A + (size_t)grow * 1152 + kc * 128 + c * 8);
      sA[(r << 4) + (c ^ (r & 7))] = v;          // XOR-swizzled 16B chunks
    }
    for (int it = tid; it < BN * 16; it += 256){
      int o = it >> 4, c = it & 15;
      sB[(o << 4) + (c ^ (o & 7))] = *reinterpret_cast<const uint4*>(Wt + (size_t)o * 1152 + kc * 128 + c * 8);
    }
    __syncthreads();
    #pragma unroll
    for (int kk = 0; kk < 4; kk++){
      bf16x8 av[2];
      #pragma unroll
      for (int m = 0; m < 2; m++){
        int row = wave * 32 + m * 16 + (lane & 15);
        int ch = (kk * 4 + (lane >> 4)) ^ (row & 7);
        av[m] = *reinterpret_cast<const bf16x8*>(reinterpret_cast<const char*>(sA) + row * 256 + ch * 16);
      }
      #pragma unroll
      for (int n = 0; n < NF; n++){
        int o = n * 16 + (lane & 15);
        int ch = (kk * 4 + (lane >> 4)) ^ (o & 7);
        bf16x8 bv = *reinterpret_cast<const bf16x8*>(reinterpret_cast<const char*>(sB) + o * 256 + ch * 16);
        #pragma unroll
        for (int m = 0; m < 2; m++)
          acc[m][n] = __builtin_amdgcn_mfma_f32_16x16x32_bf16(av[m], bv, acc[m][n], 0, 0, 0);
      }
    }
    __syncthreads();
  }
  // epilogue: D frag layout col=lane&15, row=(lane>>4)*4+j  [m89-verified]
  #pragma unroll
  for (int n = 0; n < NF; n++){
    int col = n * 16 + (lane & 15);
    float bv = bias[col];
    #pragma unroll
    for (int m = 0; m < 2; m++){
      #pragma unroll
      for (int j = 0; j < 4; j++){
        int row = row0 + wave * 32 + m * 16 + ((lane >> 4) << 2) + j;
        if (row < M){
          float v = acc[m][n][j] + bv;
          if (MODE == 1){
            v = fmaxf(v, 0.f) * mask[(size_t)row * 128 + col];
            reinterpret_cast<short*>(outp)[(size_t)row * 128 + col] = (short)f2bf(v);
          } else {
            reinterpret_cast<float*>(outp)[(size_t)row * BN + col] = v;
          }
        }
      }
    }
  }
}

extern "C" void kernel_launch(void* const* d_in, const int* in_sizes, int n_in,
                              void* d_out, int out_size, void* d_ws, size_t ws_size,
                              hipStream_t stream){
  const float* x    = (const float*)d_in[0];
  const int*   ei   = (const int*)d_in[1];
  const int*   et   = (const int*)d_in[2];
  const float* W1   = (const float*)d_in[3];
  const float* r1   = (const float*)d_in[4];
  const float* b1   = (const float*)d_in[5];
  const float* W2   = (const float*)d_in[6];
  const float* r2   = (const float*)d_in[7];
  const float* b2   = (const float*)d_in[8];
  const float* mask = (const float*)d_in[9];
  int N = in_sizes[0] / 128;
  int E = in_sizes[2];

  char* ws = (char*)d_ws;
  short*    A1   = (short*)(ws + 0);            // [N][1152] bf16, reused for layer 2
  short*    xb   = (short*)(ws + 115200000);    // [N][128] bf16
  short*    hb   = (short*)(ws + 128000000);    // [N][128] bf16
  short*    Wt1  = (short*)(ws + 140800000);    // [128][1152] bf16
  short*    Wt2  = (short*)(ws + 141094912);    // [64][1152] bf16
  int*      degr = (int*)(ws + 141242368);      // [8][N]
  int*      cnt  = (int*)(ws + 142842368);      // [N]
  int*      fill = (int*)(ws + 143042368);      // [N]
  int*      incl = (int*)(ws + 143242368);      // [N]
  int*      offs = (int*)(ws + 143442368);      // [N]
  int*      bsum = (int*)(ws + 143642368);      // [256]
  unsigned* idx  = (unsigned*)(ws + 143643392); // [E]
  if (ws_size < (size_t)143643392 + (size_t)E * 4) return;  // fail loudly (poison stays)

  // zero degr+cnt+fill (contiguous, N*40 bytes)
  hipMemsetAsync(degr, 0, (size_t)N * 40, stream);

  int NB = (N + 255) / 256;
  k_cvt_w<<<(128*1152 + 64*1152 + 255)/256, 256, 0, stream>>>(W1, r1, W2, r2, Wt1, Wt2);
  k_cvt_x<<<(N*32 + 255)/256, 256, 0, stream>>>(x, (uint2*)xb, N*32);
  k_count<<<(E + 255)/256, 256, 0, stream>>>(ei, et, cnt, degr, E, N);
  k_scan1<<<NB, 256, 0, stream>>>(cnt, incl, bsum, N);
  k_scan2<<<1, 256, 0, stream>>>(bsum, NB);
  k_fin<<<NB, 256, 0, stream>>>(cnt, incl, bsum, offs, N);
  k_fill<<<(E + 255)/256, 256, 0, stream>>>(ei, et, offs, fill, idx, E, N);

  // layer 1
  k_agg<<<(N + 3)/4, 256, 0, stream>>>(xb, cnt, offs, idx, degr, A1, N);
  k_gemm<8, 1><<<(N + 127)/128, 256, 0, stream>>>(A1, Wt1, b1, mask, hb, N);
  // layer 2 (same CSR, same degrees)
  k_agg<<<(N + 3)/4, 256, 0, stream>>>(hb, cnt, offs, idx, degr, A1, N);
  k_gemm<4, 2><<<(N + 127)/128, 256, 0, stream>>>(A1, Wt2, b2, nullptr, d_out, N);
}